// Round 2
// baseline (244.875 us; speedup 1.0000x reference)
//
#include <hip/hip_runtime.h>

#define NPIX   65536          // B*H*W = 16*64*64
#define CCH    64             // channels
#define KCODE  1024           // codebook size
#define HW     4096           // H*W
#define Q_ELEMS 4194304       // B*C*H*W
#define LOSS0_OFF 4194304
#define LOSS1_OFF 4194305
#define IDX_OFF   4194306

// numpy pairwise_sum middle branch (8 <= n <= 128) for n=64, on squares:
// r[j] = v[j]^2 + v[j+8]^2 + ... ; res = ((r0+r1)+(r2+r3)) + ((r4+r5)+(r6+r7))
// All mults/adds non-contractible to replicate np.sum(x*x, axis=1) bit-exactly.
template <typename F>
__device__ __forceinline__ float np_pairwise64_sq(F v) {
    float r[8];
#pragma unroll
    for (int j = 0; j < 8; ++j) r[j] = __fmul_rn(v(j), v(j));
#pragma unroll
    for (int i = 8; i < 64; i += 8) {
#pragma unroll
        for (int j = 0; j < 8; ++j)
            r[j] = __fadd_rn(r[j], __fmul_rn(v(i + j), v(i + j)));
    }
    return __fadd_rn(
        __fadd_rn(__fadd_rn(r[0], r[1]), __fadd_rn(r[2], r[3])),
        __fadd_rn(__fadd_rn(r[4], r[5]), __fadd_rn(r[6], r[7])));
}

// ---- pass 1: np.sum(emb*emb, axis=1) with numpy's exact summation order ----
__global__ void ee_kernel(const float* __restrict__ emb, float* __restrict__ se) {
    int k = blockIdx.x * blockDim.x + threadIdx.x;
    if (k < KCODE) {
        const float* e = emb + (size_t)k * CCH;
        se[k] = np_pairwise64_sq([&](int i) { return e[i]; });
    }
}

// ---- pass 2: fused distance + argmin + gather + STE + losses ----
// Block = 256 threads = 4 waves over 64 pixels; each wave scans a K-quarter.
__launch_bounds__(256, 4)
__global__ void vq_kernel(const float* __restrict__ z,
                          const float* __restrict__ emb,
                          const float* __restrict__ se,
                          float* __restrict__ out) {
    const int lane = threadIdx.x & 63;
    const int wave = __builtin_amdgcn_readfirstlane(threadIdx.x >> 6);
    const int p  = blockIdx.x * 64 + lane;       // pixel id = b*4096 + h*64 + w
    const int b  = p >> 12;
    const int hw = p & 4095;

    // this pixel's channel vector (coalesced across lanes per c)
    const float* zp = z + ((size_t)b * CCH) * HW + hw;
    float zf[CCH];
#pragma unroll
    for (int c = 0; c < CCH; ++c) zf[c] = zp[(size_t)c * HW];

    // szz = np.sum(zf*zf) in numpy's exact order
    const float szz = np_pairwise64_sq([&](int i) { return zf[i]; });

    // d_k = fl( fl(szz + se_k) - (2z).e_k ), where the (2z).e_k BLAS chain
    // equals 2*(sequential fma chain of z.e_k) exactly (pow2 scaling).
    float bestd = 3.0e38f;
    int   bidx  = 0;
    const int k0 = wave * (KCODE / 4);
    for (int k = k0; k < k0 + KCODE / 4; k += 2) {
        const float* e0 = emb + (size_t)k * CCH;   // wave-uniform -> s_load
        const float* e1 = e0 + CCH;
        float d0 = 0.f, d1 = 0.f;
#pragma unroll
        for (int c = 0; c < CCH; ++c) {
            d0 = __builtin_fmaf(zf[c], e0[c], d0);
            d1 = __builtin_fmaf(zf[c], e1[c], d1);
        }
        float s0 = __fsub_rn(__fadd_rn(szz, se[k]),     __fadd_rn(d0, d0));
        float s1 = __fsub_rn(__fadd_rn(szz, se[k + 1]), __fadd_rn(d1, d1));
        if (s0 < bestd) { bestd = s0; bidx = k; }       // strict <: first-index tie-break
        if (s1 < bestd) { bestd = s1; bidx = k + 1; }
    }

    // combine the 4 K-quarters (in ascending-k order to keep np.argmin ties)
    __shared__ float sdist[4][64];
    __shared__ int   sidx[4][64];
    sdist[wave][lane] = bestd;
    sidx[wave][lane]  = bidx;
    __syncthreads();

    if (wave == 0) {
#pragma unroll
        for (int w = 1; w < 4; ++w) {
            float dw = sdist[w][lane];
            int   iw = sidx[w][lane];
            if (dw < bestd) { bestd = dw; bidx = iw; }
        }

        out[IDX_OFF + p] = (float)bidx;

        // gather chosen row; q = fl(z + fl(e - z)) replicates the STE rounding
        const float* ef = emb + (size_t)bidx * CCH;
        float lsum = 0.f;
#pragma unroll
        for (int j = 0; j < CCH / 4; ++j) {
            float4 v = *(const float4*)(ef + j * 4);
            const int c = j * 4;
            float e[4] = {v.x, v.y, v.z, v.w};
#pragma unroll
            for (int u = 0; u < 4; ++u) {
                float zc   = zf[c + u];
                float diff = __fsub_rn(e[u], zc);
                out[((size_t)(b * CCH + c + u)) * HW + hw] = __fadd_rn(zc, diff);
                lsum = __builtin_fmaf(diff, diff, lsum);
            }
        }

        // wave reduction of loss partial, one atomic per block
#pragma unroll
        for (int off = 32; off > 0; off >>= 1) lsum += __shfl_down(lsum, off, 64);
        if (lane == 0) {
            float t = lsum * (1.0f / (float)Q_ELEMS);
            atomicAdd(out + LOSS0_OFF, t);   // codebook_loss
            atomicAdd(out + LOSS1_OFF, t);   // commitment_loss (same fwd value)
        }
    }
}

extern "C" void kernel_launch(void* const* d_in, const int* in_sizes, int n_in,
                              void* d_out, int out_size, void* d_ws, size_t ws_size,
                              hipStream_t stream) {
    const float* z   = (const float*)d_in[0];
    const float* emb = (const float*)d_in[1];
    float* out = (float*)d_out;
    float* se  = (float*)d_ws;    // 1024 floats of scratch

    // zero the two loss accumulators (harness poisons d_out with 0xAA)
    hipMemsetAsync((char*)d_out + (size_t)LOSS0_OFF * sizeof(float), 0,
                   2 * sizeof(float), stream);

    ee_kernel<<<dim3(KCODE / 256), dim3(256), 0, stream>>>(emb, se);
    vq_kernel<<<dim3(NPIX / 64), dim3(256), 0, stream>>>(z, emb, se, out);
}

// Round 3
// 216.140 us; speedup vs baseline: 1.1329x; 1.1329x over previous
//
#include <hip/hip_runtime.h>

#define NPIX   65536          // B*H*W
#define CCH    64
#define KCODE  1024
#define HW     4096
#define Q_ELEMS 4194304
#define LOSS0_OFF 4194304
#define LOSS1_OFF 4194305
#define IDX_OFF   4194306
#define PTILE  16             // pixels per block

// numpy pairwise_sum middle branch for n=64 on squares (bit-exact np.sum(x*x))
template <typename F>
__device__ __forceinline__ float np_pairwise64_sq(F v) {
    float r[8];
#pragma unroll
    for (int j = 0; j < 8; ++j) r[j] = __fmul_rn(v(j), v(j));
#pragma unroll
    for (int i = 8; i < 64; i += 8) {
#pragma unroll
        for (int j = 0; j < 8; ++j)
            r[j] = __fadd_rn(r[j], __fmul_rn(v(i + j), v(i + j)));
    }
    return __fadd_rn(
        __fadd_rn(__fadd_rn(r[0], r[1]), __fadd_rn(r[2], r[3])),
        __fadd_rn(__fadd_rn(r[4], r[5]), __fadd_rn(r[6], r[7])));
}

// prep: transpose emb -> et[c][k], se[k] = np.sum(emb[k]^2), zero loss slots
__global__ void prep_kernel(const float* __restrict__ emb,
                            float* __restrict__ se, float* __restrict__ et,
                            float* __restrict__ out) {
    const int tid = blockIdx.x * 256 + threadIdx.x;   // 0..65535
    const int c = tid >> 10, k = tid & 1023;
    et[tid] = emb[k * CCH + c];                        // coalesced write
    if (tid < KCODE) {
        const float* e = emb + (size_t)tid * CCH;
        se[tid] = np_pairwise64_sq([&](int i) { return e[i]; });
    }
    if (tid == 0) { out[LOSS0_OFF] = 0.f; out[LOSS1_OFF] = 0.f; }
}

// main: block = 256 thr = 4 waves; lanes = codes; 16 pixels per block.
__launch_bounds__(256, 4)
__global__ void vq_kernel(const float* __restrict__ z,
                          const float* __restrict__ emb,
                          const float* __restrict__ se,
                          const float* __restrict__ et,
                          float* __restrict__ out) {
    __shared__ float s_szz[PTILE];
    __shared__ unsigned long long s_cand[PTILE][257];  // +pad: kill 32-way column conflict
    __shared__ unsigned long long s_part[PTILE][16];
    __shared__ unsigned int s_k[PTILE];
    __shared__ float s_red[4];

    const int t    = threadIdx.x;
    const int lane = t & 63;
    const int wave = t >> 6;
    const int pg0  = blockIdx.x * PTILE;
    const int b    = pg0 >> 12;
    const int hw0  = pg0 & 4095;
    const float* zb = z + (size_t)b * CCH * HW + hw0;  // zb[c*HW + p], wave-uniform

    // szz for the block's 16 pixels (np order), lanes 0..15 of wave 0
    if (t < PTILE)
        s_szz[t] = np_pairwise64_sq([&](int i) { return zb[(size_t)i * HW + t]; });
    __syncthreads();

    float szzv[PTILE];
#pragma unroll
    for (int p = 0; p < PTILE; ++p) szzv[p] = s_szz[p];

    unsigned long long best[PTILE];
#pragma unroll
    for (int p = 0; p < PTILE; ++p) best[p] = ~0ULL;

    for (int j = 0; j < 4; ++j) {
        const int kk = ((wave << 2) + j) * 64 + lane;   // this thread's code
        const float sek = se[kk];                        // coalesced VGPR load
        const float* ecol = et + kk;
        float acc[PTILE];
#pragma unroll
        for (int p = 0; p < PTILE; ++p) acc[p] = 0.f;

#pragma unroll 8
        for (int c = 0; c < CCH; ++c) {
            const float ev = ecol[c << 10];              // E^T[c][kk], 256B/wave
            float zrow[PTILE];                            // 16 uniform scalars -> s_load_dwordx16
#pragma unroll
            for (int p = 0; p < PTILE; ++p) zrow[p] = zb[(size_t)c * HW + p];
#pragma unroll
            for (int p = 0; p < PTILE; ++p)
                acc[p] = __builtin_fmaf(zrow[p], ev, acc[p]);  // same chain as R2
        }

#pragma unroll
        for (int p = 0; p < PTILE; ++p) {
            // d = fl( fl(szz+se) - 2*dot )  (identical algebra to R2, absmax 0)
            float d = __fsub_rn(__fadd_rn(szzv[p], sek), __fadd_rn(acc[p], acc[p]));
            unsigned long long cand =
                ((unsigned long long)__float_as_uint(d) << 32) | (unsigned)kk;
            best[p] = cand < best[p] ? cand : best[p];   // d>0 -> bit-order == value-order
        }
    }

#pragma unroll
    for (int p = 0; p < PTILE; ++p) s_cand[p][t] = best[p];
    __syncthreads();

    {   // stage 2: 256 threads, each folds 16 of the 256 candidates of pixel t&15
        const int p = t & 15, g = t >> 4;
        unsigned long long m = s_cand[p][(g << 4)];
#pragma unroll
        for (int u = 1; u < 16; ++u) {
            unsigned long long v = s_cand[p][(g << 4) + u];
            m = v < m ? v : m;
        }
        s_part[p][g] = m;
    }
    __syncthreads();

    if (t < PTILE) {   // stage 3: final per-pixel min; packed low bits = first-index k
        unsigned long long m = s_part[t][0];
#pragma unroll
        for (int g = 1; g < 16; ++g) {
            unsigned long long v = s_part[t][g];
            m = v < m ? v : m;
        }
        const unsigned int k = (unsigned int)m;
        s_k[t] = k;
        out[IDX_OFF + pg0 + t] = (float)k;
    }
    __syncthreads();

    // epilogue: thread t -> pixel p=t&15, channels c = (t>>4) + 16u
    float lsum = 0.f;
    {
        const int p = t & 15, g = t >> 4;
        const int k = (int)s_k[p];
#pragma unroll
        for (int u = 0; u < 4; ++u) {
            const int c = g + (u << 4);
            float e    = emb[(size_t)k * CCH + c];
            float zc   = zb[(size_t)c * HW + p];
            float diff = __fsub_rn(e, zc);               // STE rounding as in R2
            out[((size_t)(b * CCH + c)) * HW + hw0 + p] = __fadd_rn(zc, diff);
            lsum = __builtin_fmaf(diff, diff, lsum);
        }
    }
#pragma unroll
    for (int off = 32; off > 0; off >>= 1) lsum += __shfl_down(lsum, off, 64);
    if (lane == 0) s_red[wave] = lsum;
    __syncthreads();
    if (t == 0) {
        float v = (s_red[0] + s_red[1] + s_red[2] + s_red[3]) * (1.0f / (float)Q_ELEMS);
        atomicAdd(out + LOSS0_OFF, v);   // codebook_loss
        atomicAdd(out + LOSS1_OFF, v);   // commitment_loss (same forward value)
    }
}

extern "C" void kernel_launch(void* const* d_in, const int* in_sizes, int n_in,
                              void* d_out, int out_size, void* d_ws, size_t ws_size,
                              hipStream_t stream) {
    const float* z   = (const float*)d_in[0];
    const float* emb = (const float*)d_in[1];
    float* out = (float*)d_out;
    float* se  = (float*)d_ws;                 // 1024 floats
    float* et  = se + KCODE;                   // 65536 floats (E^T)

    prep_kernel<<<dim3(256), dim3(256), 0, stream>>>(emb, se, et, out);
    vq_kernel<<<dim3(NPIX / PTILE), dim3(256), 0, stream>>>(z, emb, se, et, out);
}